// Round 1
// baseline (30997.769 us; speedup 1.0000x reference)
//
#include <hip/hip_runtime.h>

// Problem constants (B=64, T=512, D=96, H=256)
constexpr int Bb = 64;
constexpr int Tt = 512;
constexpr int Dd = 96;
constexpr int Hh = 256;
constexpr int BH = Bb * Hh;          // 16384 floats per state buffer
#define NPER 128                      // blocks per chain

__device__ __forceinline__ float sigf(float v) { return 1.0f / (1.0f + __expf(-v)); }

// cache-bypassing (agent-scope) load/store for cross-block state exchange
__device__ __forceinline__ float aload(const float* p) {
    return __hip_atomic_load(p, __ATOMIC_RELAXED, __HIP_MEMORY_SCOPE_AGENT);
}
__device__ __forceinline__ void astore(float* p, float v) {
    __hip_atomic_store(p, v, __ATOMIC_RELAXED, __HIP_MEMORY_SCOPE_AGENT);
}

// ws layout (floats):
//  [0*BH]  h_g0 (2 bufs)   [2*BH] h_g1 (2 bufs)
//  [4*BH]  h_l0 (2 bufs)   [6*BH] h_l1 (2 bufs)
//  [8*BH]  c_l0 (1 buf)    [9*BH] c_l1 (1 buf)
//  [10*BH] barrier counters (uint): gru cnt @ +0, gru flag @ +32, lstm cnt @ +64, lstm flag @ +96
extern "C" __global__ void __launch_bounds__(512, 2)
rnn_persist(const float* __restrict__ x, const int* __restrict__ lengths,
            const float* __restrict__ gW0, const float* __restrict__ gU0,
            const float* __restrict__ gbi0, const float* __restrict__ gbr0,
            const float* __restrict__ gW1, const float* __restrict__ gU1,
            const float* __restrict__ gbi1, const float* __restrict__ gbr1,
            const float* __restrict__ lW0, const float* __restrict__ lU0,
            const float* __restrict__ lb0,
            const float* __restrict__ lW1, const float* __restrict__ lU1,
            const float* __restrict__ lb1,
            const float* __restrict__ outW, const float* __restrict__ outb,
            float* __restrict__ out, float* __restrict__ ws)
{
    const int tid  = threadIdx.x;
    const int lane = tid & 63;
    const int wave = tid >> 6;
    const int chain = blockIdx.x & 1;      // 0 = GRU, 1 = LSTM
    const int cb    = blockIdx.x >> 1;     // 0..127 within chain
    const int r0    = (cb >> 2) * 2;       // 2 rows per block
    const int j0    = (cb & 3) * 64;       // 64-wide j tile of H

    unsigned* bar = (unsigned*)(ws + 10 * BH);
    unsigned* cnt = bar + chain * 64;
    unsigned* flg = bar + chain * 64 + 32;

    __shared__ __align__(16) float sAa[2][256];   // "a" input rows (x_t or lower-layer h)
    __shared__ __align__(16) float sAh[2][256];   // own-layer h rows (previous step)
    __shared__ __align__(16) float sG[768];       // gate outputs (GRU: P@0, Q@384; LSTM: 512 used)

    const int len0 = lengths[r0];
    const int len1 = lengths[r0 + 1];
    unsigned round = 0;

    for (int t = 0; t < Tt; ++t) {
        const int wb = t & 1;        // write buffer for this step
        const int rb = wb ^ 1;       // read buffer (previous step's h)

        for (int l = 0; l < 2; ++l) {
            if (chain == 0) {
                // ================= GRU layer l =================
                const float* Wp = l ? gW1 : gW0;
                const float* Up = l ? gU1 : gU0;
                const float* bi = l ? gbi1 : gbi0;
                const float* br = l ? gbr1 : gbr0;
                float* own = ws + (l ? 2 * BH : 0);
                const float* hprev = own + rb * BH;
                float* hnext = own + wb * BH;
                const float* asrc = ws + wb * BH;  // h_g0 current step (l==1 only)
                const int Ka = l ? Hh : Dd;

                // stage A into LDS
                for (int i = tid; i < 2 * Ka; i += 512) {
                    int r = i / Ka, k = i - r * Ka;
                    sAa[r][k] = l ? aload(&asrc[(r0 + r) * Hh + k])
                                  : x[(r0 + r) * Tt * Dd + t * Dd + k];
                }
                for (int i = tid; i < 2 * Hh; i += 512) {
                    int r = i >> 8, k = i & 255;
                    sAh[r][k] = aload(&hprev[(r0 + r) * Hh + k]);
                }
                __syncthreads();

                // 12 strip tasks: 0..5 = Q (h@U, K=256), 6..11 = P (a@W, K=Ka)
                for (int s = wave; s < 12; s += 8) {
                    const int isP = (s >= 6);
                    const int u = isP ? s - 6 : s;
                    const int row = u / 3, gate = u - row * 3;
                    const int col = gate * Hh + j0 + lane;
                    const float* Wm = isP ? Wp : Up;
                    const float* Ap = isP ? sAa[row] : sAh[row];
                    const int K = isP ? Ka : Hh;
                    float acc = isP ? bi[col] : br[col];
                    #pragma unroll 2
                    for (int k = 0; k < K; k += 4) {
                        float4 a4 = *(const float4*)(Ap + k);
                        acc = fmaf(a4.x, Wm[(k + 0) * 768 + col], acc);
                        acc = fmaf(a4.y, Wm[(k + 1) * 768 + col], acc);
                        acc = fmaf(a4.z, Wm[(k + 2) * 768 + col], acc);
                        acc = fmaf(a4.w, Wm[(k + 3) * 768 + col], acc);
                    }
                    sG[(isP ? 0 : 384) + (row * 3 + gate) * 64 + lane] = acc;
                }
                __syncthreads();

                // state update (block-local): 2 rows x 64 j
                if (tid < 128) {
                    const int row = tid >> 6, j = lane;
                    float Pz = sG[(row * 3 + 0) * 64 + j];
                    float Pr = sG[(row * 3 + 1) * 64 + j];
                    float Ph = sG[(row * 3 + 2) * 64 + j];
                    float Qz = sG[384 + (row * 3 + 0) * 64 + j];
                    float Qr = sG[384 + (row * 3 + 1) * 64 + j];
                    float Qh = sG[384 + (row * 3 + 2) * 64 + j];
                    float z  = sigf(Pz + Qz);
                    float r  = sigf(Pr + Qr);
                    float hh = tanhf(Ph + r * Qh);
                    float hold = sAh[row][j0 + j];
                    float hn = z * hold + (1.0f - z) * hh;
                    if (t >= (row ? len1 : len0)) hn = hold;
                    astore(&hnext[(r0 + row) * Hh + j0 + j], hn);
                    if (l == 1) {  // fused head partial: o1 . outW[0:256]
                        float v = hn * outW[j0 + j];
                        for (int o = 32; o > 0; o >>= 1) v += __shfl_down(v, o);
                        if (j == 0) atomicAdd(&out[(r0 + row) * Tt + t], v);
                    }
                }
            } else {
                // ================= LSTM layer l =================
                const float* Wm = l ? lW1 : lW0;
                const float* Um = l ? lU1 : lU0;
                const float* bb = l ? lb1 : lb0;
                float* own = ws + (l ? 6 * BH : 4 * BH);
                const float* hprev = own + rb * BH;
                float* hnext = own + wb * BH;
                float* cbuf = ws + (8 + l) * BH;   // block-private, single buffer
                const float* asrc = ws + 4 * BH + wb * BH;  // h_l0 current step (l==1)
                const int Ka = l ? Hh : Dd;

                for (int i = tid; i < 2 * Ka; i += 512) {
                    int r = i / Ka, k = i - r * Ka;
                    sAa[r][k] = l ? aload(&asrc[(r0 + r) * Hh + k])
                                  : x[(r0 + r) * Tt * Dd + t * Dd + k];
                }
                for (int i = tid; i < 2 * Hh; i += 512) {
                    int r = i >> 8, k = i & 255;
                    sAh[r][k] = aload(&hprev[(r0 + r) * Hh + k]);
                }
                __syncthreads();

                {   // 8 strip tasks, one per wave: (row, gate)
                    const int row = wave >> 2, gate = wave & 3;
                    const int col = gate * Hh + j0 + lane;
                    float acc = bb[col];
                    #pragma unroll 2
                    for (int k = 0; k < Ka; k += 4) {
                        float4 a4 = *(const float4*)(sAa[row] + k);
                        acc = fmaf(a4.x, Wm[(k + 0) * 1024 + col], acc);
                        acc = fmaf(a4.y, Wm[(k + 1) * 1024 + col], acc);
                        acc = fmaf(a4.z, Wm[(k + 2) * 1024 + col], acc);
                        acc = fmaf(a4.w, Wm[(k + 3) * 1024 + col], acc);
                    }
                    #pragma unroll 2
                    for (int k = 0; k < Hh; k += 4) {
                        float4 a4 = *(const float4*)(sAh[row] + k);
                        acc = fmaf(a4.x, Um[(k + 0) * 1024 + col], acc);
                        acc = fmaf(a4.y, Um[(k + 1) * 1024 + col], acc);
                        acc = fmaf(a4.z, Um[(k + 2) * 1024 + col], acc);
                        acc = fmaf(a4.w, Um[(k + 3) * 1024 + col], acc);
                    }
                    sG[(row * 4 + gate) * 64 + lane] = acc;
                }
                __syncthreads();

                if (tid < 128) {
                    const int row = tid >> 6, j = lane;
                    float gi = sG[(row * 4 + 0) * 64 + j];
                    float gf = sG[(row * 4 + 1) * 64 + j];
                    float gc = sG[(row * 4 + 2) * 64 + j];
                    float go = sG[(row * 4 + 3) * 64 + j];
                    float i_ = sigf(gi), f_ = sigf(gf);
                    float cold = cbuf[(r0 + row) * Hh + j0 + j];  // block-private
                    float cn = f_ * cold + i_ * tanhf(gc);
                    float hn = sigf(go) * tanhf(cn);
                    float hold = sAh[row][j0 + j];
                    if (t >= (row ? len1 : len0)) { hn = hold; cn = cold; }
                    astore(&hnext[(r0 + row) * Hh + j0 + j], hn);
                    cbuf[(r0 + row) * Hh + j0 + j] = cn;
                    if (l == 1) {  // fused head partial: o2 . outW[256:512] (+ out_b once)
                        float v = hn * outW[Hh + j0 + j];
                        for (int o = 32; o > 0; o >>= 1) v += __shfl_down(v, o);
                        if (j == 0)
                            atomicAdd(&out[(r0 + row) * Tt + t],
                                      v + (j0 == 0 ? outb[0] : 0.0f));
                    }
                }
            }

            // ---- per-chain device-scope barrier (monotonic, no reset) ----
            __syncthreads();
            ++round;
            if (tid == 0) {
                __threadfence();
                unsigned old = __hip_atomic_fetch_add(cnt, 1u, __ATOMIC_ACQ_REL,
                                                      __HIP_MEMORY_SCOPE_AGENT);
                if (old == round * NPER - 1u) {
                    __hip_atomic_store(flg, round, __ATOMIC_RELEASE,
                                       __HIP_MEMORY_SCOPE_AGENT);
                } else {
                    while (__hip_atomic_load(flg, __ATOMIC_ACQUIRE,
                                             __HIP_MEMORY_SCOPE_AGENT) < round) {
                        __builtin_amdgcn_s_sleep(8);
                    }
                }
                __threadfence();
            }
            __syncthreads();
        }
    }
}

extern "C" void kernel_launch(void* const* d_in, const int* in_sizes, int n_in,
                              void* d_out, int out_size, void* d_ws, size_t ws_size,
                              hipStream_t stream) {
    const float* x       = (const float*)d_in[0];
    const int*   lengths = (const int*)d_in[1];
    const float* gW0  = (const float*)d_in[2];
    const float* gU0  = (const float*)d_in[3];
    const float* gbi0 = (const float*)d_in[4];
    const float* gbr0 = (const float*)d_in[5];
    const float* gW1  = (const float*)d_in[6];
    const float* gU1  = (const float*)d_in[7];
    const float* gbi1 = (const float*)d_in[8];
    const float* gbr1 = (const float*)d_in[9];
    const float* lW0  = (const float*)d_in[10];
    const float* lU0  = (const float*)d_in[11];
    const float* lb0  = (const float*)d_in[12];
    const float* lW1  = (const float*)d_in[13];
    const float* lU1  = (const float*)d_in[14];
    const float* lb1  = (const float*)d_in[15];
    const float* outW = (const float*)d_in[16];
    const float* outb = (const float*)d_in[17];
    float* out = (float*)d_out;
    float* ws  = (float*)d_ws;

    // zero state buffers + barrier counters (ws re-poisoned to 0xAA each call)
    hipMemsetAsync(d_ws, 0, (size_t)(10 * BH) * sizeof(float) + 1024, stream);
    // zero output (head accumulates via atomicAdd)
    hipMemsetAsync(d_out, 0, (size_t)out_size * sizeof(float), stream);

    rnn_persist<<<dim3(256), dim3(512), 0, stream>>>(
        x, lengths, gW0, gU0, gbi0, gbr0, gW1, gU1, gbi1, gbr1,
        lW0, lU0, lb0, lW1, lU1, lb1, outW, outb, out, ws);
}

// Round 2
// 17477.637 us; speedup vs baseline: 1.7736x; 1.7736x over previous
//
#include <hip/hip_runtime.h>

// Problem constants (B=64, T=512, D=96, H=256)
constexpr int Bb = 64;
constexpr int Tt = 512;
constexpr int Dd = 96;
constexpr int Hh = 256;
constexpr int BH = Bb * Hh;          // 16384 floats per state buffer
#define NPER 128                      // blocks per chain barrier group

__device__ __forceinline__ float sigf(float v) { return 1.0f / (1.0f + __expf(-v)); }

__device__ __forceinline__ float aload(const float* p) {
    return __hip_atomic_load(p, __ATOMIC_RELAXED, __HIP_MEMORY_SCOPE_AGENT);
}
__device__ __forceinline__ void astore(float* p, float v) {
    __hip_atomic_store(p, v, __ATOMIC_RELAXED, __HIP_MEMORY_SCOPE_AGENT);
}

// ws layout (floats):
//  [0]     h_g0 (2 bufs)   [2*BH] h_g1 (2 bufs)
//  [4*BH]  h_l0 (2 bufs)   [6*BH] h_l1 (2 bufs)
//  [8*BH]  c_l0            [9*BH] c_l1
//  [10*BH] barrier: gru cnt@+0 flag@+32, lstm cnt@+64 flag@+96
extern "C" __global__ void __launch_bounds__(512, 2)
rnn_persist(const float* __restrict__ x, const int* __restrict__ lengths,
            const float* __restrict__ gW0, const float* __restrict__ gU0,
            const float* __restrict__ gbi0, const float* __restrict__ gbr0,
            const float* __restrict__ gW1, const float* __restrict__ gU1,
            const float* __restrict__ gbi1, const float* __restrict__ gbr1,
            const float* __restrict__ lW0, const float* __restrict__ lU0,
            const float* __restrict__ lb0,
            const float* __restrict__ lW1, const float* __restrict__ lU1,
            const float* __restrict__ lb1,
            const float* __restrict__ outW, const float* __restrict__ outb,
            float* __restrict__ out, float* __restrict__ ws)
{
    const int tid  = threadIdx.x;
    const int lane = tid & 63;
    const int wave = tid >> 6;

    // block role: chain (GRU/LSTM), layer (0/1), row-group (16 x 4 rows), j-tile (4 x 64)
    const int chain = blockIdx.x & 1;
    const int half  = blockIdx.x >> 1;   // 0..127
    const int layer = half >> 6;         // 0 or 1
    const int sub   = half & 63;         // 0..63
    const int rowbase = (sub >> 2) * 4;  // 4 rows per block
    const int j0      = (sub & 3) * 64;  // 64 h-cols per block

    unsigned* bar = (unsigned*)(ws + 10 * BH);
    unsigned* cnt = bar + chain * 64;
    unsigned* flg = bar + chain * 64 + 32;

    // LDS
    __shared__ __align__(16) float4 sAT[512];     // A^T[k][4 rows]
    __shared__ float sG[6 * 256];                 // [slot][row4][col64]
    __shared__ const float* sMat0[4];
    __shared__ const float* sMat1[4];
    __shared__ int sAoff[4], sK[4], sCb0[4], sCb1[4], sSlot0[4], sSlot1[4], sDual[4];
    __shared__ int sPerw;

    const int ld = chain ? 1024 : 768;
    const int Ka = layer ? Hh : Dd;      // depth of the "a" part of A
    const int KA = Ka + Hh;              // total A depth

    if (tid == 0) {
        if (chain == 0) {
            const float* W = layer ? gW1 : gW0;
            const float* U = layer ? gU1 : gU0;
            // e0: P gates z,r ; e1: P gate h ; e2: Q gates z,r ; e3: Q gate h
            sMat0[0]=W; sMat1[0]=W; sCb0[0]=0;      sCb1[0]=Hh;    sSlot0[0]=0; sSlot1[0]=1; sDual[0]=1; sAoff[0]=0;  sK[0]=Ka;
            sMat0[1]=W; sMat1[1]=W; sCb0[1]=2*Hh;   sCb1[1]=2*Hh;  sSlot0[1]=2; sSlot1[1]=2; sDual[1]=0; sAoff[1]=0;  sK[1]=Ka;
            sMat0[2]=U; sMat1[2]=U; sCb0[2]=0;      sCb1[2]=Hh;    sSlot0[2]=3; sSlot1[2]=4; sDual[2]=1; sAoff[2]=Ka; sK[2]=Hh;
            sMat0[3]=U; sMat1[3]=U; sCb0[3]=2*Hh;   sCb1[3]=2*Hh;  sSlot0[3]=5; sSlot1[3]=5; sDual[3]=0; sAoff[3]=Ka; sK[3]=Hh;
        } else {
            const float* W = layer ? lW1 : lW0;
            const float* U = layer ? lU1 : lU0;
            sMat0[0]=W; sMat1[0]=W; sCb0[0]=0;      sCb1[0]=Hh;    sSlot0[0]=0; sSlot1[0]=1; sDual[0]=1; sAoff[0]=0;  sK[0]=Ka;
            sMat0[1]=W; sMat1[1]=W; sCb0[1]=2*Hh;   sCb1[1]=3*Hh;  sSlot0[1]=2; sSlot1[1]=3; sDual[1]=1; sAoff[1]=0;  sK[1]=Ka;
            sMat0[2]=U; sMat1[2]=U; sCb0[2]=0;      sCb1[2]=Hh;    sSlot0[2]=0; sSlot1[2]=1; sDual[2]=1; sAoff[2]=Ka; sK[2]=Hh;
            sMat0[3]=U; sMat1[3]=U; sCb0[3]=2*Hh;   sCb1[3]=3*Hh;  sSlot0[3]=2; sSlot1[3]=3; sDual[3]=1; sAoff[3]=Ka; sK[3]=Hh;
        }
        sPerw = (2 * Ka + 2 * Hh) / 8;   // 88 (layer0) or 128 (layer1), exact
    }

    const int nslot = (chain == 0) ? 6 : 4;

    // state buffer bases
    float* own   = ws + (chain ? 4 * BH : 0) + (layer ? 2 * BH : 0);
    const float* lower = ws + (chain ? 4 * BH : 0);   // layer-0 h of this chain
    float* cbuf  = ws + (8 + layer) * BH;             // LSTM only, block-private slice

    const int mylen = (tid < 256) ? lengths[rowbase + (tid >> 6)] : 0;
    const float* myBi = chain ? (layer ? lb1 : lb0) : (layer ? gbi1 : gbi0);
    const float* myBr = chain ? nullptr : (layer ? gbr1 : gbr0);

    __syncthreads();
    const int perw = sPerw;
    unsigned round = 0;

    for (int rd = 0; rd <= Tt; ++rd) {
        const bool active = layer == 0 ? (rd < Tt) : (rd >= 1);
        const int t = layer == 0 ? rd : rd - 1;

        if (active) {
            const int wb = t & 1, rb = wb ^ 1;
            const float* own_prev = own + rb * BH;
            float*       own_next = own + wb * BH;
            const float* low_cur  = lower + wb * BH;

            // ---- zero gate accumulators + stage A^T ----
            for (int i = tid; i < nslot * 256; i += 512) sG[i] = 0.0f;
            for (int idx = tid; idx < KA * 4; idx += 512) {
                const int r = idx & 3, k = idx >> 2;
                float v;
                if (k < Ka)
                    v = layer ? aload(&low_cur[(rowbase + r) * Hh + k])
                              : x[(rowbase + r) * Tt * Dd + t * Dd + k];
                else
                    v = aload(&own_prev[(rowbase + r) * Hh + (k - Ka)]);
                ((float*)sAT)[idx] = v;
            }
            __syncthreads();

            // ---- GEMM: each wave walks its flat k-range over the 4 class entries ----
            {
                int flat = wave * perw, rem = perw;
                int ci = 0, cs = 0;
                while (flat >= cs + sK[ci]) { cs += sK[ci]; ++ci; }
                int k0 = flat - cs;
                while (rem > 0) {
                    int len = sK[ci] - k0; if (len > rem) len = rem;
                    const float* p0 = sMat0[ci] + sCb0[ci] + j0 + lane + (size_t)k0 * ld;
                    const float* p1 = sMat1[ci] + sCb1[ci] + j0 + lane + (size_t)k0 * ld;
                    const float4* A = sAT + sAoff[ci] + k0;
                    float4 a0 = {0,0,0,0}, a1 = {0,0,0,0};
                    int k = 0;
                    if (len >= 16) {
                        float b0[16], b1[16];
                        #pragma unroll
                        for (int i = 0; i < 16; ++i) { b0[i] = p0[i * ld]; b1[i] = p1[i * ld]; }
                        while (k + 16 <= len) {
                            float n0[16], n1[16];
                            if (k + 32 <= len) {
                                #pragma unroll
                                for (int i = 0; i < 16; ++i) {
                                    n0[i] = p0[(k + 16 + i) * ld];
                                    n1[i] = p1[(k + 16 + i) * ld];
                                }
                            }
                            #pragma unroll
                            for (int i = 0; i < 16; ++i) {
                                const float4 av = A[k + i];
                                a0.x = fmaf(b0[i], av.x, a0.x);
                                a0.y = fmaf(b0[i], av.y, a0.y);
                                a0.z = fmaf(b0[i], av.z, a0.z);
                                a0.w = fmaf(b0[i], av.w, a0.w);
                                a1.x = fmaf(b1[i], av.x, a1.x);
                                a1.y = fmaf(b1[i], av.y, a1.y);
                                a1.z = fmaf(b1[i], av.z, a1.z);
                                a1.w = fmaf(b1[i], av.w, a1.w);
                            }
                            #pragma unroll
                            for (int i = 0; i < 16; ++i) { b0[i] = n0[i]; b1[i] = n1[i]; }
                            k += 16;
                        }
                    }
                    #pragma unroll 2
                    for (; k < len; ++k) {
                        const float w0 = p0[k * ld], w1 = p1[k * ld];
                        const float4 av = A[k];
                        a0.x = fmaf(w0, av.x, a0.x); a0.y = fmaf(w0, av.y, a0.y);
                        a0.z = fmaf(w0, av.z, a0.z); a0.w = fmaf(w0, av.w, a0.w);
                        a1.x = fmaf(w1, av.x, a1.x); a1.y = fmaf(w1, av.y, a1.y);
                        a1.z = fmaf(w1, av.z, a1.z); a1.w = fmaf(w1, av.w, a1.w);
                    }
                    const int s0 = sSlot0[ci];
                    atomicAdd(&sG[s0 * 256 +   0 + lane], a0.x);
                    atomicAdd(&sG[s0 * 256 +  64 + lane], a0.y);
                    atomicAdd(&sG[s0 * 256 + 128 + lane], a0.z);
                    atomicAdd(&sG[s0 * 256 + 192 + lane], a0.w);
                    if (sDual[ci]) {
                        const int s1 = sSlot1[ci];
                        atomicAdd(&sG[s1 * 256 +   0 + lane], a1.x);
                        atomicAdd(&sG[s1 * 256 +  64 + lane], a1.y);
                        atomicAdd(&sG[s1 * 256 + 128 + lane], a1.z);
                        atomicAdd(&sG[s1 * 256 + 192 + lane], a1.w);
                    }
                    rem -= len; k0 = 0; ++ci;
                }
            }
            __syncthreads();

            // ---- state update: 256 threads = 4 rows x 64 cols ----
            if (tid < 256) {
                const int r = tid >> 6, cc = lane;
                const int grow = rowbase + r, col = j0 + cc;
                const float hold = ((const float*)sAT)[(Ka + col) * 4 + r];
                const bool frozen = (t >= mylen);
                float hn;
                if (chain == 0) {
                    const float Pz = sG[0 * 256 + r * 64 + cc];
                    const float Pr = sG[1 * 256 + r * 64 + cc];
                    const float Ph = sG[2 * 256 + r * 64 + cc];
                    const float Qz = sG[3 * 256 + r * 64 + cc];
                    const float Qr = sG[4 * 256 + r * 64 + cc];
                    const float Qh = sG[5 * 256 + r * 64 + cc];
                    const float z  = sigf(Pz + Qz + myBi[col] + myBr[col]);
                    const float rr = sigf(Pr + Qr + myBi[Hh + col] + myBr[Hh + col]);
                    const float hh = tanhf(Ph + myBi[2 * Hh + col] + rr * (Qh + myBr[2 * Hh + col]));
                    hn = z * hold + (1.0f - z) * hh;
                    if (frozen) hn = hold;
                    astore(&own_next[grow * Hh + col], hn);
                    if (layer == 1) {
                        float v = hn * outW[col];
                        for (int o = 32; o > 0; o >>= 1) v += __shfl_down(v, o);
                        if (cc == 0) atomicAdd(&out[grow * Tt + t], v);
                    }
                } else {
                    const float gi = sG[0 * 256 + r * 64 + cc] + myBi[col];
                    const float gf = sG[1 * 256 + r * 64 + cc] + myBi[Hh + col];
                    const float gc = sG[2 * 256 + r * 64 + cc] + myBi[2 * Hh + col];
                    const float go = sG[3 * 256 + r * 64 + cc] + myBi[3 * Hh + col];
                    const float i_ = sigf(gi), f_ = sigf(gf);
                    const float cold = cbuf[grow * Hh + col];
                    float cn = f_ * cold + i_ * tanhf(gc);
                    hn = sigf(go) * tanhf(cn);
                    if (frozen) { hn = hold; cn = cold; }
                    astore(&own_next[grow * Hh + col], hn);
                    cbuf[grow * Hh + col] = cn;
                    if (layer == 1) {
                        float v = hn * outW[Hh + col];
                        for (int o = 32; o > 0; o >>= 1) v += __shfl_down(v, o);
                        if (cc == 0)
                            atomicAdd(&out[grow * Tt + t], v + (j0 == 0 ? outb[0] : 0.0f));
                    }
                }
            }
        }

        // ---- per-chain device barrier (monotonic counter) ----
        __syncthreads();
        ++round;
        if (tid == 0) {
            __threadfence();
            unsigned old = __hip_atomic_fetch_add(cnt, 1u, __ATOMIC_ACQ_REL,
                                                  __HIP_MEMORY_SCOPE_AGENT);
            if (old == round * NPER - 1u) {
                __hip_atomic_store(flg, round, __ATOMIC_RELEASE,
                                   __HIP_MEMORY_SCOPE_AGENT);
            } else {
                while (__hip_atomic_load(flg, __ATOMIC_ACQUIRE,
                                         __HIP_MEMORY_SCOPE_AGENT) < round) {
                    __builtin_amdgcn_s_sleep(2);
                }
            }
            __threadfence();
        }
        __syncthreads();
    }
}

extern "C" void kernel_launch(void* const* d_in, const int* in_sizes, int n_in,
                              void* d_out, int out_size, void* d_ws, size_t ws_size,
                              hipStream_t stream) {
    const float* x       = (const float*)d_in[0];
    const int*   lengths = (const int*)d_in[1];
    const float* gW0  = (const float*)d_in[2];
    const float* gU0  = (const float*)d_in[3];
    const float* gbi0 = (const float*)d_in[4];
    const float* gbr0 = (const float*)d_in[5];
    const float* gW1  = (const float*)d_in[6];
    const float* gU1  = (const float*)d_in[7];
    const float* gbi1 = (const float*)d_in[8];
    const float* gbr1 = (const float*)d_in[9];
    const float* lW0  = (const float*)d_in[10];
    const float* lU0  = (const float*)d_in[11];
    const float* lb0  = (const float*)d_in[12];
    const float* lW1  = (const float*)d_in[13];
    const float* lU1  = (const float*)d_in[14];
    const float* lb1  = (const float*)d_in[15];
    const float* outW = (const float*)d_in[16];
    const float* outb = (const float*)d_in[17];
    float* out = (float*)d_out;
    float* ws  = (float*)d_ws;

    hipMemsetAsync(d_ws, 0, (size_t)(10 * BH) * sizeof(float) + 1024, stream);
    hipMemsetAsync(d_out, 0, (size_t)out_size * sizeof(float), stream);

    rnn_persist<<<dim3(256), dim3(512), 0, stream>>>(
        x, lengths, gW0, gU0, gbi0, gbr0, gW1, gU1, gbi1, gbr1,
        lW0, lU0, lb0, lW1, lU1, lb1, outW, outb, out, ws);
}

// Round 3
// 14461.751 us; speedup vs baseline: 2.1434x; 1.2085x over previous
//
#include <hip/hip_runtime.h>

// B=64, T=512, D=96, H=256
constexpr int Bb = 64;
constexpr int Tt = 512;
constexpr int Dd = 96;
constexpr int Hh = 256;
constexpr int BH = Bb * Hh;   // 16384 floats per h buffer

__device__ __forceinline__ float sigf(float v) { return 1.0f / (1.0f + __expf(-v)); }

__device__ __forceinline__ float aload(const float* p) {
    return __hip_atomic_load(p, __ATOMIC_RELAXED, __HIP_MEMORY_SCOPE_AGENT);
}
__device__ __forceinline__ void astore(float* p, float v) {
    __hip_atomic_store(p, v, __ATOMIC_RELAXED, __HIP_MEMORY_SCOPE_AGENT);
}

template<int G>
__device__ __forceinline__ void load8(float* wv, const float* __restrict__ M,
                                      int ld, int kb) {
    #pragma unroll
    for (int u = 0; u < 8; ++u)
        #pragma unroll
        for (int g = 0; g < G; ++g)
            wv[u * G + g] = M[(long)(kb + u) * ld + g * Hh];
}

template<int G>
__device__ __forceinline__ void fma8(const float* wv, const float* __restrict__ sA,
                                     int kb, float4* acc) {
    #pragma unroll
    for (int u = 0; u < 8; ++u) {
        const float4 a4 = *(const float4*)(sA + (size_t)(kb + u) * 4);
        #pragma unroll
        for (int g = 0; g < G; ++g) {
            const float w = wv[u * G + g];
            acc[g].x = fmaf(w, a4.x, acc[g].x);
            acc[g].y = fmaf(w, a4.y, acc[g].y);
            acc[g].z = fmaf(w, a4.z, acc[g].z);
            acc[g].w = fmaf(w, a4.w, acc[g].w);
        }
    }
}

// M is pre-offset by the column position; U additionally pre-shifted by -Ka*ld
template<int G>
__device__ __forceinline__ void gemm_range(const float* __restrict__ M, int ld,
                                           const float* __restrict__ sA,
                                           int k0, int k1, float4* acc) {
    const int n8 = (k1 - k0) >> 3;
    float wv0[8 * G], wv1[8 * G];
    if (n8 > 0) {
        load8<G>(wv0, M, ld, k0);
        int c = 0;
        for (; c + 2 <= n8; c += 2) {
            load8<G>(wv1, M, ld, k0 + (c + 1) * 8);
            fma8<G>(wv0, sA, k0 + c * 8, acc);
            if (c + 2 < n8) load8<G>(wv0, M, ld, k0 + (c + 2) * 8);
            fma8<G>(wv1, sA, k0 + (c + 1) * 8, acc);
        }
        if (c < n8) fma8<G>(wv0, sA, k0 + c * 8, acc);
    }
    for (int k = k0 + (n8 << 3); k < k1; ++k) {
        const float4 a4 = *(const float4*)(sA + (size_t)k * 4);
        #pragma unroll
        for (int g = 0; g < G; ++g) {
            const float w = M[(long)k * ld + g * Hh];
            acc[g].x = fmaf(w, a4.x, acc[g].x);
            acc[g].y = fmaf(w, a4.y, acc[g].y);
            acc[g].z = fmaf(w, a4.z, acc[g].z);
            acc[g].w = fmaf(w, a4.w, acc[g].w);
        }
    }
}

__device__ __forceinline__ void addslot(float* sG, int slot, int lane, const float4& a) {
    atomicAdd(&sG[slot * 256 +   0 + lane], a.x);
    atomicAdd(&sG[slot * 256 +  64 + lane], a.y);
    atomicAdd(&sG[slot * 256 + 128 + lane], a.z);
    atomicAdd(&sG[slot * 256 + 192 + lane], a.w);
}

// ws layout (floats):
//   [0]    h_g0 x2   [2*BH] h_g1 x2   [4*BH] h_l0 x2   [6*BH] h_l1 x2
//   [8*BH] flags: 256 slots x 32 ints (128B spacing) = 32KB
// LSTM c lives in registers (block-private columns).
extern "C" __global__ void __launch_bounds__(512, 2)
rnn_persist(const float* __restrict__ x, const int* __restrict__ lengths,
            const float* __restrict__ gW0, const float* __restrict__ gU0,
            const float* __restrict__ gbi0, const float* __restrict__ gbr0,
            const float* __restrict__ gW1, const float* __restrict__ gU1,
            const float* __restrict__ gbi1, const float* __restrict__ gbr1,
            const float* __restrict__ lW0, const float* __restrict__ lU0,
            const float* __restrict__ lb0,
            const float* __restrict__ lW1, const float* __restrict__ lU1,
            const float* __restrict__ lb1,
            const float* __restrict__ outW, const float* __restrict__ outb,
            float* __restrict__ out, float* __restrict__ ws)
{
    const int tid  = threadIdx.x;
    const int lane = tid & 63;
    const int wave = tid >> 6;

    // blockIdx = rg*16 + slice; slice = chain*8 + layer*4 + jt
    // => XCD (blockIdx%8) is constant per (layer,jt): weight slice stays L2-resident.
    const int slice = blockIdx.x & 15;
    const int rg    = blockIdx.x >> 4;        // 0..15, 4 rows each
    const int chain = slice >> 3;             // 0 GRU, 1 LSTM
    const int layer = (slice >> 2) & 1;
    const int jt    = slice & 3;              // 64-col tile of H
    const int rowbase = rg * 4;
    const int cpos  = jt * 64 + lane;

    int* flags = (int*)(ws + 8 * BH);
    int* myflag = flags + (((chain * 2 + layer) * 16 + rg) * 4 + jt) * 32;

    const int Ka = layer ? Hh : Dd;           // depth of "a" part
    const int KA = Ka + Hh;                   // total K (352 or 512), both /8
    const int ld = chain ? 4 * Hh : 3 * Hh;

    const float* Wm; const float* Um;
    if (chain == 0) { Wm = layer ? gW1 : gW0; Um = layer ? gU1 : gU0; }
    else            { Wm = layer ? lW1 : lW0; Um = layer ? lU1 : lU0; }
    const float* Wp = Wm + cpos;
    const float* Up = Um + cpos - (long)Ka * ld;   // so index k>=Ka addresses row k-Ka

    float* own = ws + (chain ? 4 * BH : 0) + (layer ? 2 * BH : 0);
    const float* lower = ws + (chain ? 4 * BH : 0);

    __shared__ __align__(16) float sA[512 * 4];   // A^T[k][4 rows]
    __shared__ float sG[4 * 256];                 // [slot][row][col64]

    // per-update-thread constants (tid<256: r=tid>>6 row, cc=tid&63 col-in-tile)
    const int r = tid >> 6, cc = tid & 63, col = jt * 64 + cc;
    int grow = 0, mylen = 0;
    float b0 = 0, b1 = 0, b2 = 0, b3 = 0, ow = 0, creg = 0.0f;
    if (tid < 256) {
        grow = rowbase + r;
        mylen = lengths[grow];
        if (chain == 0) {
            const float* bi = layer ? gbi1 : gbi0;
            const float* br = layer ? gbr1 : gbr0;
            b0 = bi[col] + br[col];
            b1 = bi[Hh + col] + br[Hh + col];
            b2 = bi[2 * Hh + col];
            b3 = br[2 * Hh + col];
        } else {
            const float* bb = layer ? lb1 : lb0;
            b0 = bb[col]; b1 = bb[Hh + col]; b2 = bb[2 * Hh + col]; b3 = bb[3 * Hh + col];
        }
        if (layer == 1) ow = outW[chain * Hh + col];
    }
    const float outb0 = outb[0];
    const int kpw = KA >> 3;   // 44 or 64 k's per wave

    for (int rd = 0; rd <= Tt; ++rd) {
        const bool active = (layer == 0) ? (rd < Tt) : (rd >= 1);
        const int t = (layer == 0) ? rd : rd - 1;

        if (active) {
            // ---- poll the 8 group flags (own-layer 4 + other-layer 4) >= rd ----
            if (wave == 0) {
                const int* fp = nullptr;
                if (lane < 8) {
                    const int pl = (lane < 4) ? layer : (1 - layer);
                    fp = flags + (((chain * 2 + pl) * 16 + rg) * 4 + (lane & 3)) * 32;
                }
                bool ok = (lane >= 8);
                for (;;) {
                    if (!ok) ok = (__hip_atomic_load(fp, __ATOMIC_ACQUIRE,
                                                     __HIP_MEMORY_SCOPE_AGENT) >= rd);
                    if ((__ballot(ok) & 0xFFull) == 0xFFull) break;
                    __builtin_amdgcn_s_sleep(1);
                }
            }
            __syncthreads();

            // ---- zero gate acc + stage A^T (coalesced over k, 4 rows) ----
            for (int i = tid; i < 4 * 256; i += 512) sG[i] = 0.0f;
            {
                const float* aprev = own + ((t - 1) & 1) * BH;      // own h(t-1)
                const float* alow  = lower + (t & 1) * BH;          // lower h(t)
                #pragma unroll
                for (int rr2 = 0; rr2 < 4; ++rr2) {
                    if (tid < KA) {
                        float v;
                        if (tid < Ka)
                            v = layer ? aload(&alow[(rowbase + rr2) * Hh + tid])
                                      : x[((long)(rowbase + rr2) * Tt + t) * Dd + tid];
                        else
                            v = aload(&aprev[(rowbase + rr2) * Hh + (tid - Ka)]);
                        sA[tid * 4 + rr2] = v;
                    }
                }
            }
            __syncthreads();

            // ---- GEMM: wave k-range, split at the W/U boundary ----
            {
                const int k0 = wave * kpw, k1 = k0 + kpw;
                if (chain == 0) {
                    float4 acc[3];
                    int a = k0, b = (k1 < Ka) ? k1 : Ka;
                    if (a < b) {
                        acc[0] = acc[1] = acc[2] = float4{0, 0, 0, 0};
                        gemm_range<3>(Wp, ld, sA, a, b, acc);
                        addslot(sG, 0, lane, acc[0]);
                        addslot(sG, 1, lane, acc[1]);
                        addslot(sG, 2, lane, acc[2]);   // Ph
                    }
                    a = (k0 > Ka) ? k0 : Ka; b = k1;
                    if (a < b) {
                        acc[0] = acc[1] = acc[2] = float4{0, 0, 0, 0};
                        gemm_range<3>(Up, ld, sA, a, b, acc);
                        addslot(sG, 0, lane, acc[0]);
                        addslot(sG, 1, lane, acc[1]);
                        addslot(sG, 3, lane, acc[2]);   // Qh kept separate (reset_after)
                    }
                } else {
                    float4 acc[4];
                    int a = k0, b = (k1 < Ka) ? k1 : Ka;
                    if (a < b) {
                        acc[0] = acc[1] = acc[2] = acc[3] = float4{0, 0, 0, 0};
                        gemm_range<4>(Wp, ld, sA, a, b, acc);
                        addslot(sG, 0, lane, acc[0]); addslot(sG, 1, lane, acc[1]);
                        addslot(sG, 2, lane, acc[2]); addslot(sG, 3, lane, acc[3]);
                    }
                    a = (k0 > Ka) ? k0 : Ka; b = k1;
                    if (a < b) {
                        acc[0] = acc[1] = acc[2] = acc[3] = float4{0, 0, 0, 0};
                        gemm_range<4>(Up, ld, sA, a, b, acc);
                        addslot(sG, 0, lane, acc[0]); addslot(sG, 1, lane, acc[1]);
                        addslot(sG, 2, lane, acc[2]); addslot(sG, 3, lane, acc[3]);
                    }
                }
            }
            __syncthreads();

            // ---- state update ----
            if (tid < 256) {
                const float s0 = sG[tid], s1 = sG[256 + tid];
                const float s2 = sG[512 + tid], s3 = sG[768 + tid];
                const float hold = sA[(Ka + col) * 4 + r];
                const bool frozen = (t >= mylen);
                float hn;
                if (chain == 0) {
                    const float z   = sigf(s0 + b0);
                    const float rr2 = sigf(s1 + b1);
                    const float hh  = tanhf(s2 + b2 + rr2 * (s3 + b3));
                    hn = z * hold + (1.0f - z) * hh;
                    if (frozen) hn = hold;
                } else {
                    const float i_ = sigf(s0 + b0);
                    const float f_ = sigf(s1 + b1);
                    float cn = f_ * creg + i_ * tanhf(s2 + b2);
                    hn = sigf(s3 + b3) * tanhf(cn);
                    if (frozen) { hn = hold; cn = creg; }
                    creg = cn;
                }
                astore(&own[(t & 1) * BH + grow * Hh + col], hn);
                if (layer == 1) {
                    float v = hn * ow;
                    for (int o = 32; o > 0; o >>= 1) v += __shfl_down(v, o);
                    if (cc == 0)
                        atomicAdd(&out[(long)grow * Tt + t],
                                  v + ((chain == 1 && jt == 0) ? outb0 : 0.0f));
                }
            }
        }

        // ---- publish: my round rd is complete ----
        __syncthreads();   // drains each thread's stores (vmcnt 0) before barrier exit
        if (tid == 0) {
            __threadfence();
            __hip_atomic_store(myflag, rd + 1, __ATOMIC_RELEASE, __HIP_MEMORY_SCOPE_AGENT);
        }
    }
}

extern "C" void kernel_launch(void* const* d_in, const int* in_sizes, int n_in,
                              void* d_out, int out_size, void* d_ws, size_t ws_size,
                              hipStream_t stream) {
    const float* x       = (const float*)d_in[0];
    const int*   lengths = (const int*)d_in[1];
    const float* gW0  = (const float*)d_in[2];
    const float* gU0  = (const float*)d_in[3];
    const float* gbi0 = (const float*)d_in[4];
    const float* gbr0 = (const float*)d_in[5];
    const float* gW1  = (const float*)d_in[6];
    const float* gU1  = (const float*)d_in[7];
    const float* gbi1 = (const float*)d_in[8];
    const float* gbr1 = (const float*)d_in[9];
    const float* lW0  = (const float*)d_in[10];
    const float* lU0  = (const float*)d_in[11];
    const float* lb0  = (const float*)d_in[12];
    const float* lW1  = (const float*)d_in[13];
    const float* lU1  = (const float*)d_in[14];
    const float* lb1  = (const float*)d_in[15];
    const float* outW = (const float*)d_in[16];
    const float* outb = (const float*)d_in[17];
    float* out = (float*)d_out;
    float* ws  = (float*)d_ws;

    // zero h buffers (8*BH floats) + flag region (32KB)
    hipMemsetAsync(d_ws, 0, (size_t)(8 * BH) * sizeof(float) + 32 * 1024, stream);
    hipMemsetAsync(d_out, 0, (size_t)out_size * sizeof(float), stream);

    rnn_persist<<<dim3(256), dim3(512), 0, stream>>>(
        x, lengths, gW0, gU0, gbi0, gbr0, gW1, gU1, gbi1, gbr1,
        lW0, lU0, lb0, lW1, lU1, lb1, outW, outb, out, ws);
}